// Round 8
// baseline (344.768 us; speedup 1.0000x reference)
//
#include <hip/hip_runtime.h>
#include <hip/hip_bf16.h>
#include <stdint.h>

#define NN   4096
#define BB   4
#define CIN  128
#define COUT 64
#define JSPL 4          // j-splits in k_out

typedef __attribute__((ext_vector_type(4))) float f32x4;
typedef __attribute__((ext_vector_type(8))) short s16x8;
typedef __attribute__((ext_vector_type(4))) int   i32x4;

// exp(sigmoid(u) - 0.5) via 2 x v_exp_f32 + 1 x v_rcp_f32
__device__ __forceinline__ float sig_exp(float u) {
    const float L = 1.4426950408889634f;      // log2(e)
    float e0 = __builtin_amdgcn_exp2f(-u * L);
    float sg = __builtin_amdgcn_rcpf(1.0f + e0);
    return __builtin_amdgcn_exp2f(__builtin_fmaf(sg, L, -0.7213475204444817f)); // -0.5*log2(e)
}

__device__ __forceinline__ short f2bf(float x) {
    unsigned u = __builtin_bit_cast(unsigned, x);
    return (short)((u + 0x8000u) >> 16);      // round-half-up bf16
}

// ---------------------------------------------------------------------------
// K1: h = node_rep @ proj_W^T + proj_b ; f1/f2 per-node scalars.
// One wave per (b,n) row; lane o = output channel. Also zeroes denom
// (first 64 blocks) so no separate k_zero launch is needed.
__global__ __launch_bounds__(256) void k_proj(
    const float* __restrict__ node_rep, const int* __restrict__ node_type,
    const float* __restrict__ pW, const float* __restrict__ pb,
    const float* __restrict__ kW, const float* __restrict__ kb,
    const float* __restrict__ vW, const float* __restrict__ vb,
    float* __restrict__ h, float* __restrict__ f1, float* __restrict__ f2,
    float* __restrict__ denom)
{
    if (blockIdx.x < (BB * NN) / 256)
        denom[blockIdx.x * 256 + threadIdx.x] = 0.0f;

    int row = blockIdx.x * 4 + (threadIdx.x >> 6);   // 0 .. B*N-1
    int o   = threadIdx.x & 63;
    int n   = row & (NN - 1);

    const f32x4* xr = (const f32x4*)(node_rep + (size_t)row * CIN);
    const f32x4* wr = (const f32x4*)(pW + (size_t)o * CIN);
    float a0 = pb[o], a1 = 0.f, a2 = 0.f, a3 = 0.f;
    #pragma unroll
    for (int c = 0; c < CIN / 4; ++c) {
        f32x4 x = xr[c], w = wr[c];
        a0 = fmaf(x[0], w[0], a0);
        a1 = fmaf(x[1], w[1], a1);
        a2 = fmaf(x[2], w[2], a2);
        a3 = fmaf(x[3], w[3], a3);
    }
    float acc = (a0 + a1) + (a2 + a3);
    h[(size_t)row * COUT + o] = acc;

    int t = node_type[n];
    float s1 = acc * kW[t * COUT + o];
    float s2 = acc * vW[t * COUT + o];
    #pragma unroll
    for (int off = 32; off; off >>= 1) {
        s1 += __shfl_xor(s1, off, 64);
        s2 += __shfl_xor(s2, off, 64);
    }
    if (o == 0) { f1[row] = s1 + kb[t]; f2[row] = s2 + vb[t]; }
}

// ---------------------------------------------------------------------------
// K2: denom[b][j] += sum over 16 i rows of exp(sigmoid(adj[i][j]*(f1+f2))-0.5)
// Thread covers 4 consecutive j (f32x4 adj loads). grid (4, 256) = 1024 blocks.
// Ping-pong prefetch of the next adj row; f1 loads are wave-uniform (scalar).
__global__ __launch_bounds__(256) void k_denom(
    const float* __restrict__ adj, const float* __restrict__ f1,
    const float* __restrict__ f2, float* __restrict__ denom)
{
    int j4 = blockIdx.x * 1024 + threadIdx.x * 4;
    int i0 = blockIdx.y * 16;

    f32x4 f2r[BB], acc[BB];
    #pragma unroll
    for (int b = 0; b < BB; ++b) {
        f2r[b] = *(const f32x4*)(f2 + b * NN + j4);
        acc[b] = (f32x4){0.f, 0.f, 0.f, 0.f};
    }

    const float* abase = adj + (size_t)i0 * NN + j4;
    f32x4 aA = *(const f32x4*)(abase);
    for (int ii = 0; ii < 16; ii += 2) {
        f32x4 aB = *(const f32x4*)(abase + (size_t)(ii + 1) * NN);
        #pragma unroll
        for (int b = 0; b < BB; ++b) {
            float fv = f1[b * NN + i0 + ii];
            #pragma unroll
            for (int q = 0; q < 4; ++q) acc[b][q] += sig_exp(aA[q] * (fv + f2r[b][q]));
        }
        if (ii + 2 < 16) aA = *(const f32x4*)(abase + (size_t)(ii + 2) * NN);
        #pragma unroll
        for (int b = 0; b < BB; ++b) {
            float fv = f1[b * NN + i0 + ii + 1];
            #pragma unroll
            for (int q = 0; q < 4; ++q) acc[b][q] += sig_exp(aB[q] * (fv + f2r[b][q]));
        }
    }
    #pragma unroll
    for (int b = 0; b < BB; ++b)
        #pragma unroll
        for (int q = 0; q < 4; ++q)
            atomicAdd(&denom[b * NN + j4 + q], acc[b][q]);
}

// ---------------------------------------------------------------------------
// K2.5: hsT[b][c][j] = bf16( h[b][j][c] / denom[b][j] )  (64x64 LDS transpose)
__global__ __launch_bounds__(256) void k_hst(
    const float* __restrict__ h, const float* __restrict__ denom,
    unsigned short* __restrict__ hsT)
{
    int b  = blockIdx.y;
    int j0 = blockIdx.x * 64;
    __shared__ float tile[64][65];
    int cx = threadIdx.x & 63;
    int ry = threadIdx.x >> 6;       // 0..3
    #pragma unroll
    for (int k = 0; k < 16; ++k) {
        int jl = k * 4 + ry;
        float rd = __builtin_amdgcn_rcpf(denom[b * NN + j0 + jl]);
        tile[jl][cx] = h[((size_t)b * NN + j0 + jl) * COUT + cx] * rd;
    }
    __syncthreads();
    #pragma unroll
    for (int k = 0; k < 16; ++k) {
        int cl = k * 4 + ry;
        hsT[((size_t)b * COUT + cl) * NN + j0 + cx] = (unsigned short)f2bf(tile[cx][cl]);
    }
}

// ---------------------------------------------------------------------------
// K3: partial out over a quarter of the j-range.  WAVE = BATCH.
// grid (NN/16, JSPL) x 256 thr. Each wave: one batch, full 1024-col j-range
// (32 chunks), ping-pong register prefetch of adj + hsT. No LDS, no barriers.
// MFMA 16x16x32 bf16, same verified A/B/C layouts as before.
__global__ __launch_bounds__(256, 4) void k_out(
    const float* __restrict__ adj, const float* __restrict__ f1,
    const float* __restrict__ f2, const unsigned short* __restrict__ hsT,
    float* __restrict__ pout)
{
    int i0   = blockIdx.x * 16;
    int jsp  = blockIdx.y;
    int b    = threadIdx.x >> 6;      // wave id = batch
    int lane = threadIdx.x & 63;
    int lrow = lane & 15;
    int lgrp = lane >> 4;

    const float*          arow = adj + (size_t)(i0 + lrow) * NN;
    const float*          f2b  = f2 + b * NN;
    const unsigned short* hsb  = hsT + ((size_t)b * COUT + lrow) * NN;
    float f1v = f1[b * NN + i0 + lrow];

    f32x4 acc0 = {0.f, 0.f, 0.f, 0.f};
    f32x4 acc1 = acc0, acc2 = acc0, acc3 = acc0;

    int jb = jsp * (NN / JSPL) + lgrp * 8;

#define LDAH(t, a0, a1, h0, h1, h2, h3) {                                  \
    int jk = jb + (t) * 32;                                                \
    a0 = *(const f32x4*)(arow + jk);                                       \
    a1 = *(const f32x4*)(arow + jk + 4);                                   \
    h0 = *(const i32x4*)(hsb + jk);                                        \
    h1 = *(const i32x4*)(hsb + (size_t)16 * NN + jk);                      \
    h2 = *(const i32x4*)(hsb + (size_t)32 * NN + jk);                      \
    h3 = *(const i32x4*)(hsb + (size_t)48 * NN + jk); }

#define COMP(t, a0, a1, h0, h1, h2, h3) {                                  \
    int jk = jb + (t) * 32;                                                \
    f32x4 s0 = *(const f32x4*)(f2b + jk);                                  \
    f32x4 s1 = *(const f32x4*)(f2b + jk + 4);                              \
    float e0 = sig_exp(a0[0] * (f1v + s0[0]));                             \
    float e1 = sig_exp(a0[1] * (f1v + s0[1]));                             \
    float e2 = sig_exp(a0[2] * (f1v + s0[2]));                             \
    float e3 = sig_exp(a0[3] * (f1v + s0[3]));                             \
    float e4 = sig_exp(a1[0] * (f1v + s1[0]));                             \
    float e5 = sig_exp(a1[1] * (f1v + s1[1]));                             \
    float e6 = sig_exp(a1[2] * (f1v + s1[2]));                             \
    float e7 = sig_exp(a1[3] * (f1v + s1[3]));                             \
    s16x8 af;                                                              \
    af[0] = f2bf(e0); af[1] = f2bf(e1); af[2] = f2bf(e2); af[3] = f2bf(e3);\
    af[4] = f2bf(e4); af[5] = f2bf(e5); af[6] = f2bf(e6); af[7] = f2bf(e7);\
    acc0 = __builtin_amdgcn_mfma_f32_16x16x32_bf16(af, __builtin_bit_cast(s16x8, h0), acc0, 0, 0, 0); \
    acc1 = __builtin_amdgcn_mfma_f32_16x16x32_bf16(af, __builtin_bit_cast(s16x8, h1), acc1, 0, 0, 0); \
    acc2 = __builtin_amdgcn_mfma_f32_16x16x32_bf16(af, __builtin_bit_cast(s16x8, h2), acc2, 0, 0, 0); \
    acc3 = __builtin_amdgcn_mfma_f32_16x16x32_bf16(af, __builtin_bit_cast(s16x8, h3), acc3, 0, 0, 0); }

    f32x4 Aa0, Aa1, Ba0, Ba1;
    i32x4 Ah0, Ah1, Ah2, Ah3, Bh0, Bh1, Bh2, Bh3;
    const int T = NN / JSPL / 32;     // 32 chunks
    LDAH(0, Aa0, Aa1, Ah0, Ah1, Ah2, Ah3);
    for (int t = 0; t < T; t += 2) {
        LDAH(t + 1, Ba0, Ba1, Bh0, Bh1, Bh2, Bh3);
        COMP(t, Aa0, Aa1, Ah0, Ah1, Ah2, Ah3);
        if (t + 2 < T) LDAH(t + 2, Aa0, Aa1, Ah0, Ah1, Ah2, Ah3);
        COMP(t + 1, Ba0, Ba1, Bh0, Bh1, Bh2, Bh3);
    }
#undef LDAH
#undef COMP

    // C/D layout: row = 4*lgrp + r, col = lrow (+16 per acc index)
    #pragma unroll
    for (int r = 0; r < 4; ++r) {
        float* orow = pout + ((size_t)(jsp * BB + b) * NN + i0 + lgrp * 4 + r) * COUT + lrow;
        orow[ 0] = acc0[r];
        orow[16] = acc1[r];
        orow[32] = acc2[r];
        orow[48] = acc3[r];
    }
}

// ---------------------------------------------------------------------------
// K4: out = sum over JSPL partials.  1024 blocks x 256 threads x f32x4.
__global__ __launch_bounds__(256) void k_ored(
    const float* __restrict__ pout, float* __restrict__ out)
{
    size_t e = ((size_t)blockIdx.x * 256 + threadIdx.x) * 4;
    f32x4 s = *(const f32x4*)(pout + e);
    #pragma unroll
    for (int sp = 1; sp < JSPL; ++sp)
        s += *(const f32x4*)(pout + (size_t)sp * BB * NN * COUT + e);
    *(f32x4*)(out + e) = s;
}

// ---------------------------------------------------------------------------
extern "C" void kernel_launch(void* const* d_in, const int* in_sizes, int n_in,
                              void* d_out, int out_size, void* d_ws, size_t ws_size,
                              hipStream_t stream)
{
    const float* node_rep = (const float*)d_in[0];
    const float* adj      = (const float*)d_in[1];
    const int*   ntype    = (const int*)  d_in[2];
    const float* pW       = (const float*)d_in[3];
    const float* pb       = (const float*)d_in[4];
    const float* kW       = (const float*)d_in[5];
    const float* kb       = (const float*)d_in[6];
    const float* vW       = (const float*)d_in[7];
    const float* vb       = (const float*)d_in[8];
    float* out = (float*)d_out;

    char* w = (char*)d_ws;
    float*          h     = (float*)(w);                       // 4 MiB
    float*          f1    = (float*)(w + 4194304);             // 64 KiB
    float*          f2    = (float*)(w + 4259840);             // 64 KiB
    float*          denom = (float*)(w + 4325376);             // 64 KiB
    unsigned short* hsT   = (unsigned short*)(w + 4390912);    // 2 MiB
    float*          pout  = (float*)(w + 6488064);             // 16 MiB (JSPL*BB*NN*COUT)

    k_proj <<<BB * NN / 4, 256, 0, stream>>>(node_rep, ntype, pW, pb, kW, kb, vW, vb, h, f1, f2, denom);
    k_denom<<<dim3(NN / 1024, NN / 16), 256, 0, stream>>>(adj, f1, f2, denom);
    k_hst  <<<dim3(NN / 64, BB), 256, 0, stream>>>(h, denom, hsT);
    k_out  <<<dim3(NN / 16, JSPL), 256, 0, stream>>>(adj, f1, f2, hsT, pout);
    k_ored <<<BB * NN * COUT / 1024, 256, 0, stream>>>(pout, out);
}

// Round 15
// 300.057 us; speedup vs baseline: 1.1490x; 1.1490x over previous
//
#include <hip/hip_runtime.h>
#include <hip/hip_bf16.h>
#include <stdint.h>

#define NN   4096
#define BB   4
#define CIN  128
#define COUT 64
#define JSPL 4          // j-splits in fallback k_out

typedef __attribute__((ext_vector_type(4))) float          f32x4;
typedef __attribute__((ext_vector_type(8))) short          s16x8;
typedef __attribute__((ext_vector_type(4))) int            i32x4;
typedef __attribute__((ext_vector_type(4))) unsigned short u16x4;

// exp(sigmoid(u) - 0.5) via 2 x v_exp_f32 + 1 x v_rcp_f32
__device__ __forceinline__ float sig_exp(float u) {
    const float L = 1.4426950408889634f;      // log2(e)
    float e0 = __builtin_amdgcn_exp2f(-u * L);
    float sg = __builtin_amdgcn_rcpf(1.0f + e0);
    return __builtin_amdgcn_exp2f(__builtin_fmaf(sg, L, -0.7213475204444817f)); // -0.5*log2(e)
}

__device__ __forceinline__ short f2bf(float x) {
    unsigned u = __builtin_bit_cast(unsigned, x);
    return (short)((u + 0x8000u) >> 16);      // round-half-up bf16
}

// ---------------------------------------------------------------------------
// K1: h = node_rep @ proj_W^T + proj_b ; f1/f2 per-node scalars.
// One wave per (b,n) row; lane o = output channel. Also zeroes the denom/rden
// slot (harmless on the primary path; needed by the fallback atomics path).
__global__ __launch_bounds__(256) void k_proj(
    const float* __restrict__ node_rep, const int* __restrict__ node_type,
    const float* __restrict__ pW, const float* __restrict__ pb,
    const float* __restrict__ kW, const float* __restrict__ kb,
    const float* __restrict__ vW, const float* __restrict__ vb,
    float* __restrict__ h, float* __restrict__ f1, float* __restrict__ f2,
    float* __restrict__ denom)
{
    if (blockIdx.x < (BB * NN) / 256)
        denom[blockIdx.x * 256 + threadIdx.x] = 0.0f;

    int row = blockIdx.x * 4 + (threadIdx.x >> 6);   // 0 .. B*N-1
    int o   = threadIdx.x & 63;
    int n   = row & (NN - 1);

    const f32x4* xr = (const f32x4*)(node_rep + (size_t)row * CIN);
    const f32x4* wr = (const f32x4*)(pW + (size_t)o * CIN);
    float a0 = pb[o], a1 = 0.f, a2 = 0.f, a3 = 0.f;
    #pragma unroll
    for (int c = 0; c < CIN / 4; ++c) {
        f32x4 x = xr[c], w = wr[c];
        a0 = fmaf(x[0], w[0], a0);
        a1 = fmaf(x[1], w[1], a1);
        a2 = fmaf(x[2], w[2], a2);
        a3 = fmaf(x[3], w[3], a3);
    }
    float acc = (a0 + a1) + (a2 + a3);
    h[(size_t)row * COUT + o] = acc;

    int t = node_type[n];
    float s1 = acc * kW[t * COUT + o];
    float s2 = acc * vW[t * COUT + o];
    #pragma unroll
    for (int off = 32; off; off >>= 1) {
        s1 += __shfl_xor(s1, off, 64);
        s2 += __shfl_xor(s2, off, 64);
    }
    if (o == 0) { f1[row] = s1 + kb[t]; f2[row] = s2 + vb[t]; }
}

// ===========================================================================
// PRIMARY PATH: single adj pass -> store E bf16 + column partials; then GEMM.
// ===========================================================================

// K2p: E[b][i][j] = bf16(sig_exp(...)), pd[iy][b][j] = sum over 16 i-rows.
// Pure streaming: f32x4 adj loads (2-deep ping-pong), coalesced 8B E stores,
// no atomics, no dependent loads. grid (NN/1024, NN/16) = (4,256), 256 thr.
__global__ __launch_bounds__(256) void k_emit(
    const float* __restrict__ adj, const float* __restrict__ f1,
    const float* __restrict__ f2, unsigned short* __restrict__ E,
    float* __restrict__ pd)
{
    int j4 = blockIdx.x * 1024 + threadIdx.x * 4;
    int i0 = blockIdx.y * 16;

    f32x4 f2r[BB], acc[BB];
    #pragma unroll
    for (int b = 0; b < BB; ++b) {
        f2r[b] = *(const f32x4*)(f2 + b * NN + j4);
        acc[b] = (f32x4){0.f, 0.f, 0.f, 0.f};
    }

    const float* abase = adj + (size_t)i0 * NN + j4;
    f32x4 cur = *(const f32x4*)(abase);
    f32x4 nxt = *(const f32x4*)(abase + NN);

    for (int ii = 0; ii < 16; ++ii) {
        f32x4 a = cur;
        cur = nxt;
        if (ii + 2 < 16) nxt = *(const f32x4*)(abase + (size_t)(ii + 2) * NN);
        int i = i0 + ii;
        #pragma unroll
        for (int b = 0; b < BB; ++b) {
            float fv = f1[b * NN + i];
            u16x4 ev;
            #pragma unroll
            for (int q = 0; q < 4; ++q) {
                float e = sig_exp(a[q] * (fv + f2r[b][q]));
                acc[b][q] += e;
                ev[q] = (unsigned short)f2bf(e);
            }
            *(u16x4*)(E + ((size_t)b * NN + i) * NN + j4) = ev;
        }
    }
    #pragma unroll
    for (int b = 0; b < BB; ++b)
        *(f32x4*)(pd + (size_t)(blockIdx.y * BB + b) * NN + j4) = acc[b];
}

// K2.1p: rden[b][j] = 1 / sum over 256 i-tiles of pd.  grid 64 x 256.
__global__ __launch_bounds__(256) void k_dred(
    const float* __restrict__ pd, float* __restrict__ rden)
{
    int gid = blockIdx.x * 256 + threadIdx.x;      // (b,j) = b*NN+j
    float s0 = 0.f, s1 = 0.f, s2 = 0.f, s3 = 0.f;
    for (int it = 0; it < 256; it += 4) {
        s0 += pd[(size_t)(it + 0) * BB * NN + gid];
        s1 += pd[(size_t)(it + 1) * BB * NN + gid];
        s2 += pd[(size_t)(it + 2) * BB * NN + gid];
        s3 += pd[(size_t)(it + 3) * BB * NN + gid];
    }
    rden[gid] = 1.0f / ((s0 + s1) + (s2 + s3));
}

// K2.5p: hsT[b][c][j] = bf16( h[b][j][c] * rden[b][j] )  (64x64 LDS transpose)
__global__ __launch_bounds__(256) void k_hst_mul(
    const float* __restrict__ h, const float* __restrict__ rden,
    unsigned short* __restrict__ hsT)
{
    int b  = blockIdx.y;
    int j0 = blockIdx.x * 64;
    __shared__ float tile[64][65];
    int cx = threadIdx.x & 63;
    int ry = threadIdx.x >> 6;       // 0..3
    #pragma unroll
    for (int k = 0; k < 16; ++k) {
        int jl = k * 4 + ry;
        tile[jl][cx] = h[((size_t)b * NN + j0 + jl) * COUT + cx] * rden[b * NN + j0 + jl];
    }
    __syncthreads();
    #pragma unroll
    for (int k = 0; k < 16; ++k) {
        int cl = k * 4 + ry;
        hsT[((size_t)b * COUT + cl) * NN + j0 + cx] = (unsigned short)f2bf(tile[cx][cl]);
    }
}

// K3p: out[b][i][c] = sum_j E[b][i][j] * hs[b][j][c]  -- pure bf16 GEMM.
// grid (NN/16, BB) x 512 thr = 8 waves; wave w owns K-chunk w*512..+512
// (16 iters of 32), 2-deep ping-pong prefetch, LDS reduce, direct out write.
// A-fragment loaded from E with the SAME (lane,elem)->k map as the B loads
// (k-permutation safe; empirically verified by rounds 2-8 passing).
__global__ __launch_bounds__(512) void k_gemm(
    const unsigned short* __restrict__ E, const unsigned short* __restrict__ hsT,
    float* __restrict__ out)
{
    int i0   = blockIdx.x * 16;
    int b    = blockIdx.y;
    int tid  = threadIdx.x;
    int wid  = tid >> 6;          // 0..7
    int lane = tid & 63;
    int lrow = lane & 15;
    int lgrp = lane >> 4;

    const unsigned short* ea  = E   + ((size_t)b * NN + i0 + lrow) * NN;
    const unsigned short* hsb = hsT + ((size_t)b * COUT + lrow) * NN;

    f32x4 acc0 = {0.f, 0.f, 0.f, 0.f};
    f32x4 acc1 = acc0, acc2 = acc0, acc3 = acc0;

    int kb = wid * (NN / 8) + lgrp * 8;

#define LD(t, av, h0, h1, h2, h3) {                                 \
    int jk = kb + (t) * 32;                                         \
    av = *(const i32x4*)(ea + jk);                                  \
    h0 = *(const i32x4*)(hsb + jk);                                 \
    h1 = *(const i32x4*)(hsb + (size_t)16 * NN + jk);               \
    h2 = *(const i32x4*)(hsb + (size_t)32 * NN + jk);               \
    h3 = *(const i32x4*)(hsb + (size_t)48 * NN + jk); }

#define MM(av, h0, h1, h2, h3) {                                    \
    s16x8 af = __builtin_bit_cast(s16x8, av);                       \
    acc0 = __builtin_amdgcn_mfma_f32_16x16x32_bf16(af, __builtin_bit_cast(s16x8, h0), acc0, 0, 0, 0); \
    acc1 = __builtin_amdgcn_mfma_f32_16x16x32_bf16(af, __builtin_bit_cast(s16x8, h1), acc1, 0, 0, 0); \
    acc2 = __builtin_amdgcn_mfma_f32_16x16x32_bf16(af, __builtin_bit_cast(s16x8, h2), acc2, 0, 0, 0); \
    acc3 = __builtin_amdgcn_mfma_f32_16x16x32_bf16(af, __builtin_bit_cast(s16x8, h3), acc3, 0, 0, 0); }

    i32x4 Aa, Ah0, Ah1, Ah2, Ah3, Ba, Bh0, Bh1, Bh2, Bh3;
    const int T = NN / 8 / 32;    // 16
    LD(0, Aa, Ah0, Ah1, Ah2, Ah3);
    for (int t = 0; t < T; t += 2) {
        LD(t + 1, Ba, Bh0, Bh1, Bh2, Bh3);
        MM(Aa, Ah0, Ah1, Ah2, Ah3);
        if (t + 2 < T) LD(t + 2, Aa, Ah0, Ah1, Ah2, Ah3);
        MM(Ba, Bh0, Bh1, Bh2, Bh3);
    }
#undef LD
#undef MM

    __shared__ float red[8][16][64];
    #pragma unroll
    for (int r = 0; r < 4; ++r) {
        red[wid][lgrp * 4 + r][ 0 + lrow] = acc0[r];
        red[wid][lgrp * 4 + r][16 + lrow] = acc1[r];
        red[wid][lgrp * 4 + r][32 + lrow] = acc2[r];
        red[wid][lgrp * 4 + r][48 + lrow] = acc3[r];
    }
    __syncthreads();

    int e2 = tid * 2;             // 512 threads x 2 floats = 16x64 tile
    int ii = e2 >> 6;
    int cc = e2 & 63;
    float sx = 0.f, sy = 0.f;
    #pragma unroll
    for (int w = 0; w < 8; ++w) {
        sx += red[w][ii][cc];
        sy += red[w][ii][cc + 1];
    }
    float* op = out + ((size_t)b * NN + i0 + ii) * COUT + cc;
    op[0] = sx; op[1] = sy;
}

// ===========================================================================
// FALLBACK PATH (round-8, proven): used when ws_size is too small for E.
// ===========================================================================

__global__ __launch_bounds__(256) void k_denom(
    const float* __restrict__ adj, const float* __restrict__ f1,
    const float* __restrict__ f2, float* __restrict__ denom)
{
    int j4 = blockIdx.x * 1024 + threadIdx.x * 4;
    int i0 = blockIdx.y * 16;

    f32x4 f2r[BB], acc[BB];
    #pragma unroll
    for (int b = 0; b < BB; ++b) {
        f2r[b] = *(const f32x4*)(f2 + b * NN + j4);
        acc[b] = (f32x4){0.f, 0.f, 0.f, 0.f};
    }

    const float* abase = adj + (size_t)i0 * NN + j4;
    f32x4 aA = *(const f32x4*)(abase);
    for (int ii = 0; ii < 16; ii += 2) {
        f32x4 aB = *(const f32x4*)(abase + (size_t)(ii + 1) * NN);
        #pragma unroll
        for (int b = 0; b < BB; ++b) {
            float fv = f1[b * NN + i0 + ii];
            #pragma unroll
            for (int q = 0; q < 4; ++q) acc[b][q] += sig_exp(aA[q] * (fv + f2r[b][q]));
        }
        if (ii + 2 < 16) aA = *(const f32x4*)(abase + (size_t)(ii + 2) * NN);
        #pragma unroll
        for (int b = 0; b < BB; ++b) {
            float fv = f1[b * NN + i0 + ii + 1];
            #pragma unroll
            for (int q = 0; q < 4; ++q) acc[b][q] += sig_exp(aB[q] * (fv + f2r[b][q]));
        }
    }
    #pragma unroll
    for (int b = 0; b < BB; ++b)
        #pragma unroll
        for (int q = 0; q < 4; ++q)
            atomicAdd(&denom[b * NN + j4 + q], acc[b][q]);
}

__global__ __launch_bounds__(256) void k_hst_rcp(
    const float* __restrict__ h, const float* __restrict__ denom,
    unsigned short* __restrict__ hsT)
{
    int b  = blockIdx.y;
    int j0 = blockIdx.x * 64;
    __shared__ float tile[64][65];
    int cx = threadIdx.x & 63;
    int ry = threadIdx.x >> 6;
    #pragma unroll
    for (int k = 0; k < 16; ++k) {
        int jl = k * 4 + ry;
        float rd = __builtin_amdgcn_rcpf(denom[b * NN + j0 + jl]);
        tile[jl][cx] = h[((size_t)b * NN + j0 + jl) * COUT + cx] * rd;
    }
    __syncthreads();
    #pragma unroll
    for (int k = 0; k < 16; ++k) {
        int cl = k * 4 + ry;
        hsT[((size_t)b * COUT + cl) * NN + j0 + cx] = (unsigned short)f2bf(tile[cx][cl]);
    }
}

__global__ __launch_bounds__(256, 4) void k_out(
    const float* __restrict__ adj, const float* __restrict__ f1,
    const float* __restrict__ f2, const unsigned short* __restrict__ hsT,
    float* __restrict__ pout)
{
    int i0   = blockIdx.x * 16;
    int jsp  = blockIdx.y;
    int b    = threadIdx.x >> 6;
    int lane = threadIdx.x & 63;
    int lrow = lane & 15;
    int lgrp = lane >> 4;

    const float*          arow = adj + (size_t)(i0 + lrow) * NN;
    const float*          f2b  = f2 + b * NN;
    const unsigned short* hsb  = hsT + ((size_t)b * COUT + lrow) * NN;
    float f1v = f1[b * NN + i0 + lrow];

    f32x4 acc0 = {0.f, 0.f, 0.f, 0.f};
    f32x4 acc1 = acc0, acc2 = acc0, acc3 = acc0;

    int jb = jsp * (NN / JSPL) + lgrp * 8;

#define LDAH(t, a0, a1, h0, h1, h2, h3) {                                  \
    int jk = jb + (t) * 32;                                                \
    a0 = *(const f32x4*)(arow + jk);                                       \
    a1 = *(const f32x4*)(arow + jk + 4);                                   \
    h0 = *(const i32x4*)(hsb + jk);                                        \
    h1 = *(const i32x4*)(hsb + (size_t)16 * NN + jk);                      \
    h2 = *(const i32x4*)(hsb + (size_t)32 * NN + jk);                      \
    h3 = *(const i32x4*)(hsb + (size_t)48 * NN + jk); }

#define COMP(t, a0, a1, h0, h1, h2, h3) {                                  \
    int jk = jb + (t) * 32;                                                \
    f32x4 s0 = *(const f32x4*)(f2b + jk);                                  \
    f32x4 s1 = *(const f32x4*)(f2b + jk + 4);                              \
    float e0 = sig_exp(a0[0] * (f1v + s0[0]));                             \
    float e1 = sig_exp(a0[1] * (f1v + s0[1]));                             \
    float e2 = sig_exp(a0[2] * (f1v + s0[2]));                             \
    float e3 = sig_exp(a0[3] * (f1v + s0[3]));                             \
    float e4 = sig_exp(a1[0] * (f1v + s1[0]));                             \
    float e5 = sig_exp(a1[1] * (f1v + s1[1]));                             \
    float e6 = sig_exp(a1[2] * (f1v + s1[2]));                             \
    float e7 = sig_exp(a1[3] * (f1v + s1[3]));                             \
    s16x8 af;                                                              \
    af[0] = f2bf(e0); af[1] = f2bf(e1); af[2] = f2bf(e2); af[3] = f2bf(e3);\
    af[4] = f2bf(e4); af[5] = f2bf(e5); af[6] = f2bf(e6); af[7] = f2bf(e7);\
    acc0 = __builtin_amdgcn_mfma_f32_16x16x32_bf16(af, __builtin_bit_cast(s16x8, h0), acc0, 0, 0, 0); \
    acc1 = __builtin_amdgcn_mfma_f32_16x16x32_bf16(af, __builtin_bit_cast(s16x8, h1), acc1, 0, 0, 0); \
    acc2 = __builtin_amdgcn_mfma_f32_16x16x32_bf16(af, __builtin_bit_cast(s16x8, h2), acc2, 0, 0, 0); \
    acc3 = __builtin_amdgcn_mfma_f32_16x16x32_bf16(af, __builtin_bit_cast(s16x8, h3), acc3, 0, 0, 0); }

    f32x4 Aa0, Aa1, Ba0, Ba1;
    i32x4 Ah0, Ah1, Ah2, Ah3, Bh0, Bh1, Bh2, Bh3;
    const int T = NN / JSPL / 32;
    LDAH(0, Aa0, Aa1, Ah0, Ah1, Ah2, Ah3);
    for (int t = 0; t < T; t += 2) {
        LDAH(t + 1, Ba0, Ba1, Bh0, Bh1, Bh2, Bh3);
        COMP(t, Aa0, Aa1, Ah0, Ah1, Ah2, Ah3);
        if (t + 2 < T) LDAH(t + 2, Aa0, Aa1, Ah0, Ah1, Ah2, Ah3);
        COMP(t + 1, Ba0, Ba1, Bh0, Bh1, Bh2, Bh3);
    }
#undef LDAH
#undef COMP

    #pragma unroll
    for (int r = 0; r < 4; ++r) {
        float* orow = pout + ((size_t)(jsp * BB + b) * NN + i0 + lgrp * 4 + r) * COUT + lrow;
        orow[ 0] = acc0[r];
        orow[16] = acc1[r];
        orow[32] = acc2[r];
        orow[48] = acc3[r];
    }
}

__global__ __launch_bounds__(256) void k_ored(
    const float* __restrict__ pout, float* __restrict__ out)
{
    size_t e = ((size_t)blockIdx.x * 256 + threadIdx.x) * 4;
    f32x4 s = *(const f32x4*)(pout + e);
    #pragma unroll
    for (int sp = 1; sp < JSPL; ++sp)
        s += *(const f32x4*)(pout + (size_t)sp * BB * NN * COUT + e);
    *(f32x4*)(out + e) = s;
}

// ---------------------------------------------------------------------------
extern "C" void kernel_launch(void* const* d_in, const int* in_sizes, int n_in,
                              void* d_out, int out_size, void* d_ws, size_t ws_size,
                              hipStream_t stream)
{
    const float* node_rep = (const float*)d_in[0];
    const float* adj      = (const float*)d_in[1];
    const int*   ntype    = (const int*)  d_in[2];
    const float* pW       = (const float*)d_in[3];
    const float* pb       = (const float*)d_in[4];
    const float* kW       = (const float*)d_in[5];
    const float* kb       = (const float*)d_in[6];
    const float* vW       = (const float*)d_in[7];
    const float* vb       = (const float*)d_in[8];
    float* out = (float*)d_out;

    char* w = (char*)d_ws;
    float*          h     = (float*)(w);                       // 4 MiB
    float*          f1    = (float*)(w + 4194304);             // 64 KiB
    float*          f2    = (float*)(w + 4259840);             // 64 KiB
    float*          rden  = (float*)(w + 4325376);             // 64 KiB (denom in fallback)
    unsigned short* hsT   = (unsigned short*)(w + 4390912);    // 2 MiB
    float*          pd    = (float*)(w + 6488064);             // 16 MiB (pout in fallback)
    unsigned short* E     = (unsigned short*)(w + 23265280);   // 128 MiB (primary only)
    const size_t NEED = 23265280ULL + (size_t)BB * NN * NN * 2ULL; // 157,483,008

    k_proj<<<BB * NN / 4, 256, 0, stream>>>(node_rep, ntype, pW, pb, kW, kb, vW, vb, h, f1, f2, rden);

    if (ws_size >= NEED) {
        // primary: one adj pass -> E + partial denoms, then pure GEMM
        k_emit   <<<dim3(NN / 1024, NN / 16), 256, 0, stream>>>(adj, f1, f2, E, pd);
        k_dred   <<<BB * NN / 256, 256, 0, stream>>>(pd, rden);
        k_hst_mul<<<dim3(NN / 64, BB), 256, 0, stream>>>(h, rden, hsT);
        k_gemm   <<<dim3(NN / 16, BB), 512, 0, stream>>>(E, hsT, out);
    } else {
        // fallback: proven round-8 pipeline
        k_denom  <<<dim3(NN / 1024, NN / 16), 256, 0, stream>>>(adj, f1, f2, rden);
        k_hst_rcp<<<dim3(NN / 64, BB), 256, 0, stream>>>(h, rden, hsT);
        k_out    <<<dim3(NN / 16, JSPL), 256, 0, stream>>>(adj, f1, f2, hsT, pd);
        k_ored   <<<BB * NN * COUT / 1024, 256, 0, stream>>>(pd, out);
    }
}